// Round 2
// baseline (30280.795 us; speedup 1.0000x reference)
//
#include <hip/hip_runtime.h>
#include <hip/hip_bf16.h>

// Problem constants (B,C,H,W) = (8,256,128,128), fp32 everywhere.
#define BB 8
#define CC 256
#define HH 128
#define WW 128
#define HW (HH*WW)        // 16384
#define NPIX (BB*HW)      // 131072

// ---------------------------------------------------------------------------
// conf = clip(1 - beta*sigmoid(20*sigmoid(x) - 4), 0, 1); also zero GN stats.
// ---------------------------------------------------------------------------
__global__ __launch_bounds__(256) void k_conf(const float* __restrict__ bl,
                                              const float* __restrict__ beta,
                                              float* __restrict__ conf,
                                              float* __restrict__ stats) {
  const int t = threadIdx.x;
  if (blockIdx.x == 0) { stats[t] = 0.f; stats[t + 256] = 0.f; }
  const int i = blockIdx.x * 256 + t;
  float x = bl[i];
  float s1 = 1.f / (1.f + expf(-x));
  float s2 = 1.f / (1.f + expf(-(20.f * s1 - 4.f)));
  float cv = 1.f - beta[0] * s2;
  conf[i] = fminf(fmaxf(cv, 0.f), 1.f);
}

// ---------------------------------------------------------------------------
// Transpose the 4 W_in matrices + out_w into [c_in][c_out].
// ---------------------------------------------------------------------------
__global__ __launch_bounds__(256) void k_tr(const float* __restrict__ W_in,
                                            const float* __restrict__ out_w,
                                            float* __restrict__ wT) {
  const int i = blockIdx.x * 256 + threadIdx.x;   // 0 .. 5*65536
  const int m = i >> 16;
  const int rr = i & 65535;
  const int c = rr >> 8;
  const int d = rr & 255;
  const float* src = (m < 4) ? (W_in + m * 65536) : out_w;
  wT[i] = src[d * 256 + c];
}

// ---------------------------------------------------------------------------
// proj[dir] = W_in[dir] @ feature (per pixel) + b_in[dir]
// ---------------------------------------------------------------------------
__global__ __launch_bounds__(256) void k_proj_gemm(const float* __restrict__ feature,
                                                   const float* __restrict__ wT,
                                                   const float* __restrict__ bias,
                                                   float* __restrict__ proj,
                                                   int vertical) {
  __shared__ float Xs[64 * 256];   // [c][px], 64 KiB
  const int t = threadIdx.x;
  const int b = blockIdx.y;
  const int p0 = blockIdx.x * 64;

  {
    const int j = t & 63, c0 = t >> 6;
#pragma unroll
    for (int cc = 0; cc < 64; ++cc) {
      int c = cc * 4 + c0;
      Xs[c * 64 + j] = feature[((b * CC + c) << 14) + p0 + j];
    }
  }
  __syncthreads();

  const int d = t;
  float acc[64];
#pragma unroll
  for (int i = 0; i < 64; ++i) acc[i] = 0.f;

#pragma unroll 4
  for (int c = 0; c < 256; ++c) {
    float w = wT[c * 256 + d];
#pragma unroll
    for (int p4 = 0; p4 < 16; ++p4) {
      float4 xv = *reinterpret_cast<const float4*>(&Xs[c * 64 + p4 * 4]);
      acc[p4 * 4 + 0] += w * xv.x;
      acc[p4 * 4 + 1] += w * xv.y;
      acc[p4 * 4 + 2] += w * xv.z;
      acc[p4 * 4 + 3] += w * xv.w;
    }
  }

  const float bia = bias[d];
#pragma unroll
  for (int jj = 0; jj < 64; ++jj) {
    int p = p0 + jj;
    int pos = vertical ? (((p & 127) << 7) + (p >> 7)) : p;
    proj[(b * HW + pos) * 256 + d] = acc[jj] + bia;
  }
}

// ---------------------------------------------------------------------------
// Gated scan, register-blocked: thread = (rbg = t>>3) x (g = t&7).
// Thread owns rows rbg*4..+3, cols g*32..+31 of W_s (4x8 float4 = 128 VGPR).
// Per step: 32 ds_read_b128 (rotated, bank-conflict-free) -> 512 FMA ->
// 3-level shfl_xor butterfly over the 8 column-group lanes -> lane g<4 owns
// seq g's gate/relu/writeback. h double-buffered in LDS, 1 barrier/step.
// ---------------------------------------------------------------------------
__global__ __launch_bounds__(512, 2) void k_scan(const float* __restrict__ proj,
                                                 const float* __restrict__ conf,
                                                 const float* __restrict__ Ws,
                                                 const float* __restrict__ b_s,
                                                 const float* __restrict__ p_bias,
                                                 float* __restrict__ accum,
                                                 int vertical, int rev, int first) {
  __shared__ __align__(16) float hbuf[2][4][CC];   // 8 KiB
  const int t = threadIdx.x;
  const int g = t & 7;          // column group (32 cols)
  const int rbg = t >> 3;       // row block (4 rows)
  const int s0 = blockIdx.x * 4;

  // weight patch: rows rbg*4..+3, cols g*32..+31
  float4 W4[4][8];
#pragma unroll
  for (int i = 0; i < 4; ++i) {
    const float* wrow = Ws + (rbg * 4 + i) * CC + g * 32;
#pragma unroll
    for (int c4 = 0; c4 < 8; ++c4)
      W4[i][c4] = *reinterpret_cast<const float4*>(wrow + c4 * 4);
  }
  const float4 bs4 = *reinterpret_cast<const float4*>(b_s + rbg * 4);
  const float4 pb4 = *reinterpret_cast<const float4*>(p_bias + rbg * 4);
  float4 cst4 = make_float4(bs4.x + pb4.x, bs4.y + pb4.y, bs4.z + pb4.z, bs4.w + pb4.w);

  // zero h
  {
    float* hb0 = &hbuf[0][0][0];
    hb0[t] = 0.f;
    hb0[t + 512] = 0.f;
  }

  const int dp = rev ? -CC : CC;
  const int dc = vertical ? (rev ? -WW : WW) : (rev ? -1 : 1);
  const int da = vertical ? (rev ? -(WW * CC) : (WW * CC)) : dp;
  const int pstart = rev ? 127 : 0;

  // per-owner-lane (g<4) sequence state for seq n = s0+g
  int pix = 0, cix = 0, aix = 0;
  if (g < 4) {
    int n = s0 + g;
    if (!vertical) {
      pix = (n * WW + pstart) * CC + rbg * 4;
      cix = n * WW + pstart;
      aix = pix;
    } else {
      int b = n >> 7, wc = n & 127;
      pix = (n * HH + pstart) * CC + rbg * 4;
      cix = b * HW + pstart * WW + wc;
      aix = (b * HW + pstart * WW + wc) * CC + rbg * 4;
    }
  }

  float4 pj = make_float4(0.f, 0.f, 0.f, 0.f), pjn = pj, ard = pj, arn = pj;
  float gg = 0.f, ggn = 0.f;
  if (g < 4) {
    pj = *reinterpret_cast<const float4*>(proj + pix);
    gg = conf[cix];
    if (!first) ard = *reinterpret_cast<const float4*>(accum + aix);
    pix += dp; cix += dc;
  }
  __syncthreads();

  for (int k = 0; k < 128; ++k) {
    // prefetch next step's operands (owner lanes only)
    if (g < 4) {
      if (k < 127) {
        pjn = *reinterpret_cast<const float4*>(proj + pix);
        ggn = conf[cix];
        if (!first) arn = *reinterpret_cast<const float4*>(accum + aix + da);
      }
    }

    // 4 seqs x 4 rows partial dots over this thread's 32 cols
    float dt[4][4];
#pragma unroll
    for (int s = 0; s < 4; ++s)
#pragma unroll
      for (int i = 0; i < 4; ++i) dt[s][i] = 0.f;

    const float* hb = &hbuf[k & 1][0][0];
#pragma unroll
    for (int j = 0; j < 8; ++j) {
      const int cj = (j + g) & 7;               // bank-spread rotation
      const int off = g * 32 + cj * 4;
#pragma unroll
      for (int s = 0; s < 4; ++s) {
        float4 hv = *reinterpret_cast<const float4*>(hb + s * CC + off);
        // static cj would be needed for W4; cj is derived from unrolled j -> static
#pragma unroll
        for (int i = 0; i < 4; ++i) {
          dt[s][i] += W4[i][cj].x * hv.x + W4[i][cj].y * hv.y +
                      W4[i][cj].z * hv.z + W4[i][cj].w * hv.w;
        }
      }
    }

    // butterfly over the 8 column-group lanes (contiguous lanes, xor 1/2/4)
#pragma unroll
    for (int s = 0; s < 4; ++s)
#pragma unroll
      for (int i = 0; i < 4; ++i) {
        float v = dt[s][i];
        v += __shfl_xor(v, 1);
        v += __shfl_xor(v, 2);
        v += __shfl_xor(v, 4);
        dt[s][i] = v;
      }

    if (g < 4) {
      // static selects (avoid runtime-indexed array -> scratch)
      float d0 = (g == 0) ? dt[0][0] : (g == 1) ? dt[1][0] : (g == 2) ? dt[2][0] : dt[3][0];
      float d1 = (g == 0) ? dt[0][1] : (g == 1) ? dt[1][1] : (g == 2) ? dt[2][1] : dt[3][1];
      float d2 = (g == 0) ? dt[0][2] : (g == 1) ? dt[1][2] : (g == 2) ? dt[2][2] : dt[3][2];
      float d3 = (g == 0) ? dt[0][3] : (g == 1) ? dt[1][3] : (g == 2) ? dt[2][3] : dt[3][3];
      float4 hn;
      hn.x = fmaxf(pj.x + gg * d0 + cst4.x, 0.f);
      hn.y = fmaxf(pj.y + gg * d1 + cst4.y, 0.f);
      hn.z = fmaxf(pj.z + gg * d2 + cst4.z, 0.f);
      hn.w = fmaxf(pj.w + gg * d3 + cst4.w, 0.f);
      *reinterpret_cast<float4*>(&hbuf[(k + 1) & 1][g][rbg * 4]) = hn;
      float4 av;
      if (first) av = hn;
      else av = make_float4(hn.x + ard.x, hn.y + ard.y, hn.z + ard.z, hn.w + ard.w);
      *reinterpret_cast<float4*>(accum + aix) = av;
      aix += da;
      pj = pjn; gg = ggn; ard = arn;
      pix += dp; cix += dc;
    }
    __syncthreads();
  }
}

// ---------------------------------------------------------------------------
// z = out_w @ fused + out_b + feature ; GN partial sums per (b, group).
// ---------------------------------------------------------------------------
__global__ __launch_bounds__(256) void k_out_gemm(const float* __restrict__ fused,
                                                  const float* __restrict__ owT,
                                                  const float* __restrict__ out_b,
                                                  const float* __restrict__ feature,
                                                  float* __restrict__ out,
                                                  float* __restrict__ stats) {
  __shared__ float Fs[64 * 256];   // [c][px]
  const int t = threadIdx.x;
  const int b = blockIdx.y;
  const int p0 = blockIdx.x * 64;

  {
    const int px = t >> 2, cq = t & 3;
    const float* src = fused + ((b * HW + p0 + px) * 256 + cq * 64);
#pragma unroll
    for (int kk = 0; kk < 16; ++kk) {
      float4 v = *reinterpret_cast<const float4*>(src + kk * 4);
      int c = cq * 64 + kk * 4;
      Fs[(c + 0) * 64 + px] = v.x; Fs[(c + 1) * 64 + px] = v.y;
      Fs[(c + 2) * 64 + px] = v.z; Fs[(c + 3) * 64 + px] = v.w;
    }
  }
  __syncthreads();

  const int d = t;
  float acc[64];
#pragma unroll
  for (int i = 0; i < 64; ++i) acc[i] = 0.f;

#pragma unroll 4
  for (int c = 0; c < 256; ++c) {
    float w = owT[c * 256 + d];
#pragma unroll
    for (int p4 = 0; p4 < 16; ++p4) {
      float4 xv = *reinterpret_cast<const float4*>(&Fs[c * 64 + p4 * 4]);
      acc[p4 * 4 + 0] += w * xv.x;
      acc[p4 * 4 + 1] += w * xv.y;
      acc[p4 * 4 + 2] += w * xv.z;
      acc[p4 * 4 + 3] += w * xv.w;
    }
  }

  const float bia = out_b[d];
  const int obase = ((b * 256 + d) << 14) + p0;
  const float* fsrc = feature + obase;
  float s1 = 0.f, s2 = 0.f;
#pragma unroll
  for (int j = 0; j < 64; ++j) {
    float z = acc[j] + bia + fsrc[j];
    out[obase + j] = z;
    s1 += z; s2 += z * z;
  }
  s1 += __shfl_xor(s1, 1); s2 += __shfl_xor(s2, 1);
  s1 += __shfl_xor(s1, 2); s2 += __shfl_xor(s2, 2);
  s1 += __shfl_xor(s1, 4); s2 += __shfl_xor(s2, 4);
  if ((d & 7) == 0) {
    int gidx = d >> 3;
    atomicAdd(&stats[(b * 32 + gidx) * 2 + 0], s1);
    atomicAdd(&stats[(b * 32 + gidx) * 2 + 1], s2);
  }
}

// ---------------------------------------------------------------------------
// In-place GroupNorm normalize of d_out using accumulated stats.
// ---------------------------------------------------------------------------
__global__ __launch_bounds__(256) void k_norm(float* __restrict__ out,
                                              const float* __restrict__ stats,
                                              const float* __restrict__ gn_w,
                                              const float* __restrict__ gn_b) {
  const int i = (blockIdx.x * 256 + threadIdx.x) << 2;
  const int c = (i >> 14) & 255;
  const int b = i >> 22;
  const int g = c >> 3;
  float s1 = stats[(b * 32 + g) * 2 + 0];
  float s2 = stats[(b * 32 + g) * 2 + 1];
  const float invN = 1.f / 131072.f;
  float mu = s1 * invN;
  float var = fmaxf(s2 * invN - mu * mu, 0.f);
  float is = rsqrtf(var + 1e-5f);
  float wmul = gn_w[c] * is;
  float badd = gn_b[c] - mu * wmul;
  float4 z = *reinterpret_cast<float4*>(&out[i]);
  z.x = z.x * wmul + badd; z.y = z.y * wmul + badd;
  z.z = z.z * wmul + badd; z.w = z.w * wmul + badd;
  *reinterpret_cast<float4*>(&out[i]) = z;
}

// ---------------------------------------------------------------------------
extern "C" void kernel_launch(void* const* d_in, const int* in_sizes, int n_in,
                              void* d_out, int out_size, void* d_ws, size_t ws_size,
                              hipStream_t stream) {
  const float* feature = (const float*)d_in[0];
  const float* blog    = (const float*)d_in[1];
  const float* beta    = (const float*)d_in[2];
  const float* W_in    = (const float*)d_in[3];
  const float* b_in    = (const float*)d_in[4];
  const float* W_s     = (const float*)d_in[5];
  const float* b_s     = (const float*)d_in[6];
  const float* p_bias  = (const float*)d_in[7];
  const float* out_w   = (const float*)d_in[8];
  const float* out_b   = (const float*)d_in[9];
  const float* gn_w    = (const float*)d_in[10];
  const float* gn_b    = (const float*)d_in[11];
  float* out = (float*)d_out;

  // workspace layout (floats): proj 33.5M | accum 33.5M | conf 128K | stats 512 | wT 320K
  float* ws    = (float*)d_ws;
  float* proj  = ws;
  float* accum = ws + 33554432;
  float* conf  = ws + 67108864;
  float* stats = ws + 67239936;
  float* wT    = ws + 67240448;    // 5 * 65536

  k_conf<<<NPIX / 256, 256, 0, stream>>>(blog, beta, conf, stats);
  k_tr<<<(5 * 65536) / 256, 256, 0, stream>>>(W_in, out_w, wT);

  for (int dir = 0; dir < 4; ++dir) {
    const int vertical = (dir >= 2);
    const int rev = (dir == 1 || dir == 3);
    k_proj_gemm<<<dim3(HW / 64, BB), 256, 0, stream>>>(
        feature, wT + dir * 65536, b_in + dir * 256, proj, vertical);
    k_scan<<<256, 512, 0, stream>>>(
        proj, conf, W_s + dir * 65536, b_s + dir * 256, p_bias + dir * 256,
        accum, vertical, rev, dir == 0);
  }

  k_out_gemm<<<dim3(HW / 64, BB), 256, 0, stream>>>(
      accum, wT + 4 * 65536, out_b, feature, out, stats);
  k_norm<<<(BB * CC * HW) / 1024, 256, 0, stream>>>(out, stats, gn_w, gn_b);
}

// Round 3
// 3496.592 us; speedup vs baseline: 8.6601x; 8.6601x over previous
//
#include <hip/hip_runtime.h>
#include <hip/hip_bf16.h>

// Problem constants (B,C,H,W) = (8,256,128,128), fp32 everywhere.
#define BB 8
#define CC 256
#define HH 128
#define WW 128
#define HW (HH*WW)        // 16384
#define NPIX (BB*HW)      // 131072

// ---------------------------------------------------------------------------
// conf = clip(1 - beta*sigmoid(20*sigmoid(x) - 4), 0, 1); also zero GN stats.
// ---------------------------------------------------------------------------
__global__ __launch_bounds__(256) void k_conf(const float* __restrict__ bl,
                                              const float* __restrict__ beta,
                                              float* __restrict__ conf,
                                              float* __restrict__ stats) {
  const int t = threadIdx.x;
  if (blockIdx.x == 0) { stats[t] = 0.f; stats[t + 256] = 0.f; }
  const int i = blockIdx.x * 256 + t;
  float x = bl[i];
  float s1 = 1.f / (1.f + expf(-x));
  float s2 = 1.f / (1.f + expf(-(20.f * s1 - 4.f)));
  float cv = 1.f - beta[0] * s2;
  conf[i] = fminf(fmaxf(cv, 0.f), 1.f);
}

// ---------------------------------------------------------------------------
// Transpose the 4 W_in matrices + out_w into [c_in][c_out].
// ---------------------------------------------------------------------------
__global__ __launch_bounds__(256) void k_tr(const float* __restrict__ W_in,
                                            const float* __restrict__ out_w,
                                            float* __restrict__ wT) {
  const int i = blockIdx.x * 256 + threadIdx.x;   // 0 .. 5*65536
  const int m = i >> 16;
  const int rr = i & 65535;
  const int c = rr >> 8;
  const int d = rr & 255;
  const float* src = (m < 4) ? (W_in + m * 65536) : out_w;
  wT[i] = src[d * 256 + c];
}

// ---------------------------------------------------------------------------
// proj[dir] = W_in[dir] @ feature (per pixel) + b_in[dir]
// ---------------------------------------------------------------------------
__global__ __launch_bounds__(256) void k_proj_gemm(const float* __restrict__ feature,
                                                   const float* __restrict__ wT,
                                                   const float* __restrict__ bias,
                                                   float* __restrict__ proj,
                                                   int vertical) {
  __shared__ float Xs[64 * 256];   // [c][px], 64 KiB
  const int t = threadIdx.x;
  const int b = blockIdx.y;
  const int p0 = blockIdx.x * 64;

  {
    const int j = t & 63, c0 = t >> 6;
#pragma unroll
    for (int cc = 0; cc < 64; ++cc) {
      int c = cc * 4 + c0;
      Xs[c * 64 + j] = feature[((b * CC + c) << 14) + p0 + j];
    }
  }
  __syncthreads();

  const int d = t;
  float acc[64];
#pragma unroll
  for (int i = 0; i < 64; ++i) acc[i] = 0.f;

#pragma unroll 4
  for (int c = 0; c < 256; ++c) {
    float w = wT[c * 256 + d];
#pragma unroll
    for (int p4 = 0; p4 < 16; ++p4) {
      float4 xv = *reinterpret_cast<const float4*>(&Xs[c * 64 + p4 * 4]);
      acc[p4 * 4 + 0] += w * xv.x;
      acc[p4 * 4 + 1] += w * xv.y;
      acc[p4 * 4 + 2] += w * xv.z;
      acc[p4 * 4 + 3] += w * xv.w;
    }
  }

  const float bia = bias[d];
#pragma unroll
  for (int jj = 0; jj < 64; ++jj) {
    int p = p0 + jj;
    int pos = vertical ? (((p & 127) << 7) + (p >> 7)) : p;
    proj[(b * HW + pos) * 256 + d] = acc[jj] + bia;
  }
}

// ---------------------------------------------------------------------------
// Gated scan, register-blocked: thread = (rbg = t>>3) x (g = t&7).
// Thread owns rows rbg*4..+3 and a PERMUTED set of column quads: register
// slot j holds column quad ((j+g)&7) of its 32-col group. The permutation is
// applied at weight-LOAD time (runtime index into GLOBAL memory = fine) so
// the inner loop indexes W4 with the STATIC unrolled j (rule #20) while the
// LDS address carries the rotation (bank-conflict-free: starts at banks
// 4*((j+g)&7), 8 x 16B covering all 32 banks, same-address lanes broadcast).
// ---------------------------------------------------------------------------
__global__ __launch_bounds__(512, 2) void k_scan(const float* __restrict__ proj,
                                                 const float* __restrict__ conf,
                                                 const float* __restrict__ Ws,
                                                 const float* __restrict__ b_s,
                                                 const float* __restrict__ p_bias,
                                                 float* __restrict__ accum,
                                                 int vertical, int rev, int first) {
  __shared__ __align__(16) float hbuf[2][4][CC];   // 8 KiB
  const int t = threadIdx.x;
  const int g = t & 7;          // column group (32 cols)
  const int rbg = t >> 3;       // row block (4 rows)
  const int s0 = blockIdx.x * 4;

  // weight patch, rotation applied at load: W4[i][j] = cols quad ((j+g)&7)
  float4 W4[4][8];
#pragma unroll
  for (int i = 0; i < 4; ++i) {
    const float* wrow = Ws + (rbg * 4 + i) * CC + g * 32;
#pragma unroll
    for (int j = 0; j < 8; ++j) {
      const int cj = (j + g) & 7;               // runtime, but global-mem index
      W4[i][j] = *reinterpret_cast<const float4*>(wrow + cj * 4);
    }
  }
  const float4 bs4 = *reinterpret_cast<const float4*>(b_s + rbg * 4);
  const float4 pb4 = *reinterpret_cast<const float4*>(p_bias + rbg * 4);
  float4 cst4 = make_float4(bs4.x + pb4.x, bs4.y + pb4.y, bs4.z + pb4.z, bs4.w + pb4.w);

  // zero h
  {
    float* hb0 = &hbuf[0][0][0];
    hb0[t] = 0.f;
    hb0[t + 512] = 0.f;
  }

  const int dp = rev ? -CC : CC;
  const int dc = vertical ? (rev ? -WW : WW) : (rev ? -1 : 1);
  const int da = vertical ? (rev ? -(WW * CC) : (WW * CC)) : dp;
  const int pstart = rev ? 127 : 0;

  // per-owner-lane (g<4) sequence state for seq n = s0+g
  int pix = 0, cix = 0, aix = 0;
  if (g < 4) {
    int n = s0 + g;
    if (!vertical) {
      pix = (n * WW + pstart) * CC + rbg * 4;
      cix = n * WW + pstart;
      aix = pix;
    } else {
      int b = n >> 7, wc = n & 127;
      pix = (n * HH + pstart) * CC + rbg * 4;
      cix = b * HW + pstart * WW + wc;
      aix = (b * HW + pstart * WW + wc) * CC + rbg * 4;
    }
  }

  float4 pj = make_float4(0.f, 0.f, 0.f, 0.f), pjn = pj, ard = pj, arn = pj;
  float gg = 0.f, ggn = 0.f;
  if (g < 4) {
    pj = *reinterpret_cast<const float4*>(proj + pix);
    gg = conf[cix];
    if (!first) ard = *reinterpret_cast<const float4*>(accum + aix);
    pix += dp; cix += dc;
  }
  __syncthreads();

  for (int k = 0; k < 128; ++k) {
    // prefetch next step's operands (owner lanes only)
    if (g < 4) {
      if (k < 127) {
        pjn = *reinterpret_cast<const float4*>(proj + pix);
        ggn = conf[cix];
        if (!first) arn = *reinterpret_cast<const float4*>(accum + aix + da);
      }
    }

    // 4 seqs x 4 rows partial dots over this thread's 32 cols
    float dt[4][4];
#pragma unroll
    for (int s = 0; s < 4; ++s)
#pragma unroll
      for (int i = 0; i < 4; ++i) dt[s][i] = 0.f;

    const float* hb = &hbuf[k & 1][0][0];
#pragma unroll
    for (int j = 0; j < 8; ++j) {
      const int off = g * 32 + (((j + g) & 7) << 2);   // runtime addr: fine
#pragma unroll
      for (int s = 0; s < 4; ++s) {
        float4 hv = *reinterpret_cast<const float4*>(hb + s * CC + off);
#pragma unroll
        for (int i = 0; i < 4; ++i) {
          dt[s][i] += W4[i][j].x * hv.x + W4[i][j].y * hv.y +
                      W4[i][j].z * hv.z + W4[i][j].w * hv.w;   // static reg idx
        }
      }
    }

    // butterfly over the 8 column-group lanes (contiguous lanes, xor 1/2/4)
#pragma unroll
    for (int s = 0; s < 4; ++s)
#pragma unroll
      for (int i = 0; i < 4; ++i) {
        float v = dt[s][i];
        v += __shfl_xor(v, 1);
        v += __shfl_xor(v, 2);
        v += __shfl_xor(v, 4);
        dt[s][i] = v;
      }

    if (g < 4) {
      // static selects (avoid runtime-indexed array -> scratch)
      float d0 = (g == 0) ? dt[0][0] : (g == 1) ? dt[1][0] : (g == 2) ? dt[2][0] : dt[3][0];
      float d1 = (g == 0) ? dt[0][1] : (g == 1) ? dt[1][1] : (g == 2) ? dt[2][1] : dt[3][1];
      float d2 = (g == 0) ? dt[0][2] : (g == 1) ? dt[1][2] : (g == 2) ? dt[2][2] : dt[3][2];
      float d3 = (g == 0) ? dt[0][3] : (g == 1) ? dt[1][3] : (g == 2) ? dt[2][3] : dt[3][3];
      float4 hn;
      hn.x = fmaxf(pj.x + gg * d0 + cst4.x, 0.f);
      hn.y = fmaxf(pj.y + gg * d1 + cst4.y, 0.f);
      hn.z = fmaxf(pj.z + gg * d2 + cst4.z, 0.f);
      hn.w = fmaxf(pj.w + gg * d3 + cst4.w, 0.f);
      *reinterpret_cast<float4*>(&hbuf[(k + 1) & 1][g][rbg * 4]) = hn;
      float4 av;
      if (first) av = hn;
      else av = make_float4(hn.x + ard.x, hn.y + ard.y, hn.z + ard.z, hn.w + ard.w);
      *reinterpret_cast<float4*>(accum + aix) = av;
      aix += da;
      pj = pjn; gg = ggn; ard = arn;
      pix += dp; cix += dc;
    }
    __syncthreads();
  }
}

// ---------------------------------------------------------------------------
// z = out_w @ fused + out_b + feature ; GN partial sums per (b, group).
// ---------------------------------------------------------------------------
__global__ __launch_bounds__(256) void k_out_gemm(const float* __restrict__ fused,
                                                  const float* __restrict__ owT,
                                                  const float* __restrict__ out_b,
                                                  const float* __restrict__ feature,
                                                  float* __restrict__ out,
                                                  float* __restrict__ stats) {
  __shared__ float Fs[64 * 256];   // [c][px]
  const int t = threadIdx.x;
  const int b = blockIdx.y;
  const int p0 = blockIdx.x * 64;

  {
    const int px = t >> 2, cq = t & 3;
    const float* src = fused + ((b * HW + p0 + px) * 256 + cq * 64);
#pragma unroll
    for (int kk = 0; kk < 16; ++kk) {
      float4 v = *reinterpret_cast<const float4*>(src + kk * 4);
      int c = cq * 64 + kk * 4;
      Fs[(c + 0) * 64 + px] = v.x; Fs[(c + 1) * 64 + px] = v.y;
      Fs[(c + 2) * 64 + px] = v.z; Fs[(c + 3) * 64 + px] = v.w;
    }
  }
  __syncthreads();

  const int d = t;
  float acc[64];
#pragma unroll
  for (int i = 0; i < 64; ++i) acc[i] = 0.f;

#pragma unroll 4
  for (int c = 0; c < 256; ++c) {
    float w = owT[c * 256 + d];
#pragma unroll
    for (int p4 = 0; p4 < 16; ++p4) {
      float4 xv = *reinterpret_cast<const float4*>(&Fs[c * 64 + p4 * 4]);
      acc[p4 * 4 + 0] += w * xv.x;
      acc[p4 * 4 + 1] += w * xv.y;
      acc[p4 * 4 + 2] += w * xv.z;
      acc[p4 * 4 + 3] += w * xv.w;
    }
  }

  const float bia = out_b[d];
  const int obase = ((b * 256 + d) << 14) + p0;
  const float* fsrc = feature + obase;
  float s1 = 0.f, s2 = 0.f;
#pragma unroll
  for (int j = 0; j < 64; ++j) {
    float z = acc[j] + bia + fsrc[j];
    out[obase + j] = z;
    s1 += z; s2 += z * z;
  }
  s1 += __shfl_xor(s1, 1); s2 += __shfl_xor(s2, 1);
  s1 += __shfl_xor(s1, 2); s2 += __shfl_xor(s2, 2);
  s1 += __shfl_xor(s1, 4); s2 += __shfl_xor(s2, 4);
  if ((d & 7) == 0) {
    int gidx = d >> 3;
    atomicAdd(&stats[(b * 32 + gidx) * 2 + 0], s1);
    atomicAdd(&stats[(b * 32 + gidx) * 2 + 1], s2);
  }
}

// ---------------------------------------------------------------------------
// In-place GroupNorm normalize of d_out using accumulated stats.
// ---------------------------------------------------------------------------
__global__ __launch_bounds__(256) void k_norm(float* __restrict__ out,
                                              const float* __restrict__ stats,
                                              const float* __restrict__ gn_w,
                                              const float* __restrict__ gn_b) {
  const int i = (blockIdx.x * 256 + threadIdx.x) << 2;
  const int c = (i >> 14) & 255;
  const int b = i >> 22;
  const int g = c >> 3;
  float s1 = stats[(b * 32 + g) * 2 + 0];
  float s2 = stats[(b * 32 + g) * 2 + 1];
  const float invN = 1.f / 131072.f;
  float mu = s1 * invN;
  float var = fmaxf(s2 * invN - mu * mu, 0.f);
  float is = rsqrtf(var + 1e-5f);
  float wmul = gn_w[c] * is;
  float badd = gn_b[c] - mu * wmul;
  float4 z = *reinterpret_cast<float4*>(&out[i]);
  z.x = z.x * wmul + badd; z.y = z.y * wmul + badd;
  z.z = z.z * wmul + badd; z.w = z.w * wmul + badd;
  *reinterpret_cast<float4*>(&out[i]) = z;
}

// ---------------------------------------------------------------------------
extern "C" void kernel_launch(void* const* d_in, const int* in_sizes, int n_in,
                              void* d_out, int out_size, void* d_ws, size_t ws_size,
                              hipStream_t stream) {
  const float* feature = (const float*)d_in[0];
  const float* blog    = (const float*)d_in[1];
  const float* beta    = (const float*)d_in[2];
  const float* W_in    = (const float*)d_in[3];
  const float* b_in    = (const float*)d_in[4];
  const float* W_s     = (const float*)d_in[5];
  const float* b_s     = (const float*)d_in[6];
  const float* p_bias  = (const float*)d_in[7];
  const float* out_w   = (const float*)d_in[8];
  const float* out_b   = (const float*)d_in[9];
  const float* gn_w    = (const float*)d_in[10];
  const float* gn_b    = (const float*)d_in[11];
  float* out = (float*)d_out;

  // workspace layout (floats): proj 33.5M | accum 33.5M | conf 128K | stats 512 | wT 320K
  float* ws    = (float*)d_ws;
  float* proj  = ws;
  float* accum = ws + 33554432;
  float* conf  = ws + 67108864;
  float* stats = ws + 67239936;
  float* wT    = ws + 67240448;    // 5 * 65536

  k_conf<<<NPIX / 256, 256, 0, stream>>>(blog, beta, conf, stats);
  k_tr<<<(5 * 65536) / 256, 256, 0, stream>>>(W_in, out_w, wT);

  for (int dir = 0; dir < 4; ++dir) {
    const int vertical = (dir >= 2);
    const int rev = (dir == 1 || dir == 3);
    k_proj_gemm<<<dim3(HW / 64, BB), 256, 0, stream>>>(
        feature, wT + dir * 65536, b_in + dir * 256, proj, vertical);
    k_scan<<<256, 512, 0, stream>>>(
        proj, conf, W_s + dir * 65536, b_s + dir * 256, p_bias + dir * 256,
        accum, vertical, rev, dir == 0);
  }

  k_out_gemm<<<dim3(HW / 64, BB), 256, 0, stream>>>(
      accum, wT + 4 * 65536, out_b, feature, out, stats);
  k_norm<<<(BB * CC * HW) / 1024, 256, 0, stream>>>(out, stats, gn_w, gn_b);
}

// Round 4
// 2973.941 us; speedup vs baseline: 10.1820x; 1.1757x over previous
//
#include <hip/hip_runtime.h>
#include <hip/hip_bf16.h>

// Problem constants (B,C,H,W) = (8,256,128,128), fp32 everywhere.
#define BB 8
#define CC 256
#define HH 128
#define WW 128
#define HW (HH*WW)        // 16384
#define NPIX (BB*HW)      // 131072

// ---------------------------------------------------------------------------
// conf = clip(1 - beta*sigmoid(20*sigmoid(x) - 4), 0, 1); also zero GN stats.
// ---------------------------------------------------------------------------
__global__ __launch_bounds__(256) void k_conf(const float* __restrict__ bl,
                                              const float* __restrict__ beta,
                                              float* __restrict__ conf,
                                              float* __restrict__ stats) {
  const int t = threadIdx.x;
  if (blockIdx.x == 0) { stats[t] = 0.f; stats[t + 256] = 0.f; }
  const int i = blockIdx.x * 256 + t;
  float x = bl[i];
  float s1 = 1.f / (1.f + expf(-x));
  float s2 = 1.f / (1.f + expf(-(20.f * s1 - 4.f)));
  float cv = 1.f - beta[0] * s2;
  conf[i] = fminf(fmaxf(cv, 0.f), 1.f);
}

// ---------------------------------------------------------------------------
// Transpose the 4 W_in matrices + out_w into [c_in][c_out].
// ---------------------------------------------------------------------------
__global__ __launch_bounds__(256) void k_tr(const float* __restrict__ W_in,
                                            const float* __restrict__ out_w,
                                            float* __restrict__ wT) {
  const int i = blockIdx.x * 256 + threadIdx.x;   // 0 .. 5*65536
  const int m = i >> 16;
  const int rr = i & 65535;
  const int c = rr >> 8;
  const int d = rr & 255;
  const float* src = (m < 4) ? (W_in + m * 65536) : out_w;
  wT[i] = src[d * 256 + c];
}

// ---------------------------------------------------------------------------
// proj[dir] = W_in[dir] @ feature (per pixel) + b_in[dir]
// Register tile: thread = (ch-quad q = t&63, px-group p = t>>6 of 16 px).
// Per c: 1 global float4 (weights, 1KB/wave contiguous) + 4 broadcast LDS
// float4 -> 64 FMA. Output float4 stores are 1KB/wave contiguous.
// ---------------------------------------------------------------------------
__global__ __launch_bounds__(256) void k_proj_gemm(const float* __restrict__ feature,
                                                   const float* __restrict__ wT,
                                                   const float* __restrict__ bias,
                                                   float* __restrict__ proj,
                                                   int vertical) {
  __shared__ float Xs[256 * 64];   // [c][px], 64 KiB
  const int t = threadIdx.x;
  const int b = blockIdx.y;
  const int p0 = blockIdx.x * 64;

  {
    const int j = t & 63, c0 = t >> 6;
#pragma unroll
    for (int cc = 0; cc < 64; ++cc) {
      int c = cc * 4 + c0;
      Xs[c * 64 + j] = feature[((b * CC + c) << 14) + p0 + j];
    }
  }
  __syncthreads();

  const int q = t & 63;     // ch quad: channels q*4..q*4+3
  const int p = t >> 6;     // px group: pixels p*16..p*16+15

  float acc[4][16];
#pragma unroll
  for (int ch = 0; ch < 4; ++ch)
#pragma unroll
    for (int px = 0; px < 16; ++px) acc[ch][px] = 0.f;

#pragma unroll 2
  for (int c = 0; c < 256; ++c) {
    const float4 w4 = *reinterpret_cast<const float4*>(wT + c * 256 + q * 4);
#pragma unroll
    for (int p4 = 0; p4 < 4; ++p4) {
      const float4 xv = *reinterpret_cast<const float4*>(&Xs[c * 64 + p * 16 + p4 * 4]);
      acc[0][p4 * 4 + 0] += w4.x * xv.x; acc[0][p4 * 4 + 1] += w4.x * xv.y;
      acc[0][p4 * 4 + 2] += w4.x * xv.z; acc[0][p4 * 4 + 3] += w4.x * xv.w;
      acc[1][p4 * 4 + 0] += w4.y * xv.x; acc[1][p4 * 4 + 1] += w4.y * xv.y;
      acc[1][p4 * 4 + 2] += w4.y * xv.z; acc[1][p4 * 4 + 3] += w4.y * xv.w;
      acc[2][p4 * 4 + 0] += w4.z * xv.x; acc[2][p4 * 4 + 1] += w4.z * xv.y;
      acc[2][p4 * 4 + 2] += w4.z * xv.z; acc[2][p4 * 4 + 3] += w4.z * xv.w;
      acc[3][p4 * 4 + 0] += w4.w * xv.x; acc[3][p4 * 4 + 1] += w4.w * xv.y;
      acc[3][p4 * 4 + 2] += w4.w * xv.z; acc[3][p4 * 4 + 3] += w4.w * xv.w;
    }
  }

  const float4 bia = *reinterpret_cast<const float4*>(bias + q * 4);
#pragma unroll
  for (int jj = 0; jj < 16; ++jj) {
    const int pp = p0 + p * 16 + jj;
    const int pos = vertical ? (((pp & 127) << 7) + (pp >> 7)) : pp;
    float4 o = make_float4(acc[0][jj] + bia.x, acc[1][jj] + bia.y,
                           acc[2][jj] + bia.z, acc[3][jj] + bia.w);
    *reinterpret_cast<float4*>(&proj[(size_t)(b * HW + pos) * 256 + q * 4]) = o;
  }
}

// ---------------------------------------------------------------------------
// Gated scan, reduce-scatter edition.
// 1024 threads = 64 rowblocks (rbg) x 16 colgroups (g). Thread owns a 4-row x
// 16-col patch of W_s (64 VGPR, fits the 1024-thread 128-VGPR cap -> no AGPR
// spill). Per step: 16 LDS b128 reads (rot cj=(j+(g>>1))&3 -> 2-way max bank
// alias = free; 4-lane broadcast) -> 256 FMA -> 4-level reduce-scatter
// (15 shfl, static indices) -> lane g owns (seq=g>>2, row=rbg*4+(g&3)):
// uniform epilogue, no divergence. 1 barrier/step.
// ---------------------------------------------------------------------------
__global__ __launch_bounds__(1024) void k_scan(const float* __restrict__ proj,
                                               const float* __restrict__ conf,
                                               const float* __restrict__ Ws,
                                               const float* __restrict__ b_s,
                                               const float* __restrict__ p_bias,
                                               float* __restrict__ accum,
                                               int vertical, int rev, int first) {
  __shared__ __align__(16) float hbuf[2][4][CC];   // 8 KiB
  const int t = threadIdx.x;
  const int g = t & 15;         // colgroup (16 cols)
  const int rbg = t >> 4;       // rowblock (4 rows)
  const int s_own = g >> 2;     // owned seq after reduce-scatter
  const int row = rbg * 4 + (g & 3);   // owned output row

  // weight patch rows rbg*4..+3, cols g*16..+15; quad j holds col-quad
  // cj=(j+(g>>1))&3 (rotation matches the LDS read below; global idx = fine).
  float4 W4[4][4];
#pragma unroll
  for (int i = 0; i < 4; ++i) {
    const float* wr = Ws + (rbg * 4 + i) * CC + g * 16;
#pragma unroll
    for (int j = 0; j < 4; ++j) {
      const int cj = (j + (g >> 1)) & 3;
      W4[i][j] = *reinterpret_cast<const float4*>(wr + cj * 4);
    }
  }
  const float cst = b_s[row] + p_bias[row];

  ((float*)hbuf)[t] = 0.f;   // zero buffer 0 (first 1024 floats)

  const int dp = rev ? -CC : CC;
  const int dc = vertical ? (rev ? -WW : WW) : (rev ? -1 : 1);
  const int da = vertical ? (rev ? -(WW * CC) : (WW * CC)) : dp;
  const int pstart = rev ? 127 : 0;

  const int n = blockIdx.x * 4 + s_own;
  int pix, cix, aix;
  if (!vertical) {
    pix = (n * WW + pstart) * CC + row;
    cix = n * WW + pstart;
    aix = pix;
  } else {
    pix = (n * HH + pstart) * CC + row;
    cix = (n >> 7) * HW + pstart * WW + (n & 127);
    aix = ((n >> 7) * HW + pstart * WW + (n & 127)) * CC + row;
  }

  float pj = proj[pix];
  float gg = conf[cix];
  float ard = first ? 0.f : accum[aix];
  pix += dp; cix += dc;
  __syncthreads();

  for (int k = 0; k < 128; ++k) {
    float pjn = 0.f, ggn = 0.f, arn = 0.f;
    if (k < 127) {
      pjn = proj[pix];
      ggn = conf[cix];
      if (!first) arn = accum[aix + da];
    }

    float dt[16];
#pragma unroll
    for (int v = 0; v < 16; ++v) dt[v] = 0.f;

    const float* hb = &hbuf[k & 1][0][0];
#pragma unroll
    for (int j = 0; j < 4; ++j) {
      const int off = g * 16 + (((j + (g >> 1)) & 3) << 2);
#pragma unroll
      for (int s = 0; s < 4; ++s) {
        const float4 hv = *reinterpret_cast<const float4*>(hb + s * CC + off);
#pragma unroll
        for (int i = 0; i < 4; ++i) {
          dt[s * 4 + i] += W4[i][j].x * hv.x + W4[i][j].y * hv.y +
                           W4[i][j].z * hv.z + W4[i][j].w * hv.w;
        }
      }
    }

    // reduce-scatter: after 4 levels lane g holds v=g fully reduced.
#pragma unroll
    for (int jj = 0; jj < 8; ++jj) {
      float send = (g & 8) ? dt[jj] : dt[jj + 8];
      float recv = __shfl_xor(send, 8);
      float keep = (g & 8) ? dt[jj + 8] : dt[jj];
      dt[jj] = keep + recv;
    }
#pragma unroll
    for (int jj = 0; jj < 4; ++jj) {
      float send = (g & 4) ? dt[jj] : dt[jj + 4];
      float recv = __shfl_xor(send, 4);
      float keep = (g & 4) ? dt[jj + 4] : dt[jj];
      dt[jj] = keep + recv;
    }
#pragma unroll
    for (int jj = 0; jj < 2; ++jj) {
      float send = (g & 2) ? dt[jj] : dt[jj + 2];
      float recv = __shfl_xor(send, 2);
      float keep = (g & 2) ? dt[jj + 2] : dt[jj];
      dt[jj] = keep + recv;
    }
    {
      float send = (g & 1) ? dt[0] : dt[1];
      float recv = __shfl_xor(send, 1);
      float keep = (g & 1) ? dt[1] : dt[0];
      dt[0] = keep + recv;
    }

    // uniform epilogue: every lane owns one (seq,row)
    const float hn = fmaxf(pj + gg * dt[0] + cst, 0.f);
    hbuf[(k + 1) & 1][s_own][row] = hn;
    accum[aix] = first ? hn : (hn + ard);
    aix += da;
    pj = pjn; gg = ggn; ard = arn;
    pix += dp; cix += dc;
    __syncthreads();
  }
}

// ---------------------------------------------------------------------------
// z = out_w @ fused + out_b + feature ; GN partial sums per (b, group).
// Register tile: thread = (px-quad pq = t&15, ch-group cg = t>>4 of 16 ch).
// Stores are float4-contiguous per channel (fixes channel-strided scalars).
// ---------------------------------------------------------------------------
__global__ __launch_bounds__(256) void k_out_gemm(const float* __restrict__ fused,
                                                  const float* __restrict__ owT,
                                                  const float* __restrict__ out_b,
                                                  const float* __restrict__ feature,
                                                  float* __restrict__ out,
                                                  float* __restrict__ stats) {
  __shared__ float Fs[256 * 64];   // [c][px]
  const int t = threadIdx.x;
  const int b = blockIdx.y;
  const int p0 = blockIdx.x * 64;

  {
    const int px = t >> 2, cq = t & 3;
    const float* src = fused + ((size_t)(b * HW + p0 + px)) * 256 + cq * 64;
#pragma unroll
    for (int kk = 0; kk < 16; ++kk) {
      float4 v = *reinterpret_cast<const float4*>(src + kk * 4);
      int c = cq * 64 + kk * 4;
      Fs[(c + 0) * 64 + px] = v.x; Fs[(c + 1) * 64 + px] = v.y;
      Fs[(c + 2) * 64 + px] = v.z; Fs[(c + 3) * 64 + px] = v.w;
    }
  }
  __syncthreads();

  const int pq = t & 15;    // px quad: pixels pq*4..+3
  const int cg = t >> 4;    // ch group: channels cg*16..+15

  float acc[16][4];
#pragma unroll
  for (int ch = 0; ch < 16; ++ch)
#pragma unroll
    for (int px = 0; px < 4; ++px) acc[ch][px] = 0.f;

#pragma unroll 2
  for (int c = 0; c < 256; ++c) {
    const float4 xv = *reinterpret_cast<const float4*>(&Fs[c * 64 + pq * 4]);
#pragma unroll
    for (int wi = 0; wi < 4; ++wi) {
      const float4 w4 = *reinterpret_cast<const float4*>(owT + c * 256 + cg * 16 + wi * 4);
      acc[wi * 4 + 0][0] += w4.x * xv.x; acc[wi * 4 + 0][1] += w4.x * xv.y;
      acc[wi * 4 + 0][2] += w4.x * xv.z; acc[wi * 4 + 0][3] += w4.x * xv.w;
      acc[wi * 4 + 1][0] += w4.y * xv.x; acc[wi * 4 + 1][1] += w4.y * xv.y;
      acc[wi * 4 + 1][2] += w4.y * xv.z; acc[wi * 4 + 1][3] += w4.y * xv.w;
      acc[wi * 4 + 2][0] += w4.z * xv.x; acc[wi * 4 + 2][1] += w4.z * xv.y;
      acc[wi * 4 + 2][2] += w4.z * xv.z; acc[wi * 4 + 2][3] += w4.z * xv.w;
      acc[wi * 4 + 3][0] += w4.w * xv.x; acc[wi * 4 + 3][1] += w4.w * xv.y;
      acc[wi * 4 + 3][2] += w4.w * xv.z; acc[wi * 4 + 3][3] += w4.w * xv.w;
    }
  }

  float s1a = 0.f, s2a = 0.f, s1b = 0.f, s2b = 0.f;
#pragma unroll
  for (int ch = 0; ch < 16; ++ch) {
    const int cabs = cg * 16 + ch;
    const float bia = out_b[cabs];
    const size_t base = ((size_t)(b * 256 + cabs) << 14) + p0 + pq * 4;
    const float4 f = *reinterpret_cast<const float4*>(feature + base);
    float4 z = make_float4(acc[ch][0] + bia + f.x, acc[ch][1] + bia + f.y,
                           acc[ch][2] + bia + f.z, acc[ch][3] + bia + f.w);
    *reinterpret_cast<float4*>(&out[base]) = z;
    float ps = z.x + z.y + z.z + z.w;
    float pq2 = z.x * z.x + z.y * z.y + z.z * z.z + z.w * z.w;
    if (ch < 8) { s1a += ps; s2a += pq2; } else { s1b += ps; s2b += pq2; }
  }
  // reduce over the 16 px-quad lanes
#pragma unroll
  for (int m = 1; m <= 8; m <<= 1) {
    s1a += __shfl_xor(s1a, m); s2a += __shfl_xor(s2a, m);
    s1b += __shfl_xor(s1b, m); s2b += __shfl_xor(s2b, m);
  }
  if (pq == 0) {
    atomicAdd(&stats[(b * 32 + cg * 2 + 0) * 2 + 0], s1a);
    atomicAdd(&stats[(b * 32 + cg * 2 + 0) * 2 + 1], s2a);
    atomicAdd(&stats[(b * 32 + cg * 2 + 1) * 2 + 0], s1b);
    atomicAdd(&stats[(b * 32 + cg * 2 + 1) * 2 + 1], s2b);
  }
}

// ---------------------------------------------------------------------------
// In-place GroupNorm normalize of d_out using accumulated stats.
// ---------------------------------------------------------------------------
__global__ __launch_bounds__(256) void k_norm(float* __restrict__ out,
                                              const float* __restrict__ stats,
                                              const float* __restrict__ gn_w,
                                              const float* __restrict__ gn_b) {
  const int i = (blockIdx.x * 256 + threadIdx.x) << 2;
  const int c = (i >> 14) & 255;
  const int b = i >> 22;
  const int g = c >> 3;
  float s1 = stats[(b * 32 + g) * 2 + 0];
  float s2 = stats[(b * 32 + g) * 2 + 1];
  const float invN = 1.f / 131072.f;
  float mu = s1 * invN;
  float var = fmaxf(s2 * invN - mu * mu, 0.f);
  float is = rsqrtf(var + 1e-5f);
  float wmul = gn_w[c] * is;
  float badd = gn_b[c] - mu * wmul;
  float4 z = *reinterpret_cast<float4*>(&out[i]);
  z.x = z.x * wmul + badd; z.y = z.y * wmul + badd;
  z.z = z.z * wmul + badd; z.w = z.w * wmul + badd;
  *reinterpret_cast<float4*>(&out[i]) = z;
}

// ---------------------------------------------------------------------------
extern "C" void kernel_launch(void* const* d_in, const int* in_sizes, int n_in,
                              void* d_out, int out_size, void* d_ws, size_t ws_size,
                              hipStream_t stream) {
  const float* feature = (const float*)d_in[0];
  const float* blog    = (const float*)d_in[1];
  const float* beta    = (const float*)d_in[2];
  const float* W_in    = (const float*)d_in[3];
  const float* b_in    = (const float*)d_in[4];
  const float* W_s     = (const float*)d_in[5];
  const float* b_s     = (const float*)d_in[6];
  const float* p_bias  = (const float*)d_in[7];
  const float* out_w   = (const float*)d_in[8];
  const float* out_b   = (const float*)d_in[9];
  const float* gn_w    = (const float*)d_in[10];
  const float* gn_b    = (const float*)d_in[11];
  float* out = (float*)d_out;

  // workspace layout (floats): proj 33.5M | accum 33.5M | conf 128K | stats 512 | wT 320K
  float* ws    = (float*)d_ws;
  float* proj  = ws;
  float* accum = ws + 33554432;
  float* conf  = ws + 67108864;
  float* stats = ws + 67239936;
  float* wT    = ws + 67240448;    // 5 * 65536

  k_conf<<<NPIX / 256, 256, 0, stream>>>(blog, beta, conf, stats);
  k_tr<<<(5 * 65536) / 256, 256, 0, stream>>>(W_in, out_w, wT);

  for (int dir = 0; dir < 4; ++dir) {
    const int vertical = (dir >= 2);
    const int rev = (dir == 1 || dir == 3);
    k_proj_gemm<<<dim3(HW / 64, BB), 256, 0, stream>>>(
        feature, wT + dir * 65536, b_in + dir * 256, proj, vertical);
    k_scan<<<256, 1024, 0, stream>>>(
        proj, conf, W_s + dir * 65536, b_s + dir * 256, p_bias + dir * 256,
        accum, vertical, rev, dir == 0);
  }

  k_out_gemm<<<dim3(HW / 64, BB), 256, 0, stream>>>(
      accum, wT + 4 * 65536, out_b, feature, out, stats);
  k_norm<<<(BB * CC * HW) / 1024, 256, 0, stream>>>(out, stats, gn_w, gn_b);
}